// Round 12
// baseline (128.587 us; speedup 1.0000x reference)
//
#include <hip/hip_runtime.h>
#include <math.h>

// Shapes: B=4096, N=128, D=64, H=256, O=128
// d_out (floats): out[B*128] | mem_new[B*128*64] | h_new[B*256] | c_new[B*256]
// ws: (unused 524288) | write_w f32 | erase f32 | addv f32 | bsum f32 | bh_b f32 |
//     bf16: Ag[4096][448]=[x|rv|h] | Aout[4096][320]=[h_new|rv] | Wg[1024][448] |
//           Wh_b[256][256] | Wo_b[128][320]

typedef __attribute__((ext_vector_type(8))) short bf16x8;
typedef __attribute__((ext_vector_type(4))) float f32x4;
typedef __attribute__((ext_vector_type(4))) unsigned short us4;

#define MFMA16(a, b, c) __builtin_amdgcn_mfma_f32_16x16x32_bf16(a, b, c, 0, 0, 0)
#define GLL16(gp, lp) __builtin_amdgcn_global_load_lds( \
    (const __attribute__((address_space(1))) void*)(gp), \
    (__attribute__((address_space(3))) void*)(lp), 16, 0, 0)
#define SW(row, s) ((s) ^ ((row) & 3))

__device__ __forceinline__ float sigf(float v) { return 1.f / (1.f + __expf(-v)); }

__device__ __forceinline__ unsigned short f2bf(float f) {
    unsigned u = __builtin_bit_cast(unsigned, f);
    u = (u + 0x7FFFu + ((u >> 16) & 1u)) >> 16;
    return (unsigned short)u;
}

// swizzled addr in an [8][320] bf16 LDS tile
__device__ __forceinline__ int swA8(int r, int c) {
    return r * 320 + (c & ~31) + ((((c >> 3) & 3) ^ (r & 3)) << 3) + (c & 7);
}

// =============== k2: pack + in-block scores/softmax + rv stream ===============
// grid 4096 (1 row/block), block 256 (4 waves).
__global__ __launch_bounds__(256) void k2_stream_pack(
    const float* __restrict__ mem,
    const float* __restrict__ x, const float* __restrict__ h,
    const float* __restrict__ Wih, const float* __restrict__ Whh,
    const float* __restrict__ bih, const float* __restrict__ bhh,
    const float* __restrict__ Wr, const float* __restrict__ br,
    const float* __restrict__ Ww, const float* __restrict__ We,
    const float* __restrict__ Wa, const float* __restrict__ bw,
    const float* __restrict__ be, const float* __restrict__ ba,
    const float* __restrict__ Wo,
    unsigned short* __restrict__ Wg, unsigned short* __restrict__ Wh_b,
    unsigned short* __restrict__ Wo_b, float* __restrict__ bsum,
    float* __restrict__ bh_b, unsigned short* __restrict__ Ag,
    unsigned short* __restrict__ Aout)
{
    __shared__ float part[16][68];
    __shared__ float scr[128];
    __shared__ float wL[128];
    int t = threadIdx.x;
    int b = blockIdx.x;
    unsigned idx = b * 256 + t;

    // ---- striped packs (fire-and-forget stores) ----
    if (idx < 458752) {
        int r = idx / 448, cc = idx - r * 448;
        float v = (cc < 192) ? Wih[(size_t)r * 192 + cc] : Whh[(size_t)r * 256 + (cc - 192)];
        Wg[idx] = f2bf(v);
    }
    if (idx < 65536) {
        int r = idx >> 8, cc = idx & 255;
        float v = (r < 128) ? Ww[(size_t)r * 256 + cc]
                : (r < 192) ? We[(size_t)(r - 128) * 256 + cc]
                            : Wa[(size_t)(r - 192) * 256 + cc];
        Wh_b[idx] = f2bf(v);
    }
    if (idx < 40960) Wo_b[idx] = f2bf(Wo[idx]);
    if (idx < 1024)  bsum[idx] = bih[idx] + bhh[idx];
    if (idx < 256)
        bh_b[idx] = (idx < 128) ? bw[idx] : (idx < 192 ? be[idx - 128] : ba[idx - 192]);

    // ---- own-row x/h pack into Ag ----
    if (t < 96) {
        int j = t;
        float4 v = (j < 32) ? ((const float4*)(x + (size_t)b * 128))[j]
                            : ((const float4*)(h + (size_t)b * 256))[j - 32];
        us4 o = { f2bf(v.x), f2bf(v.y), f2bf(v.z), f2bf(v.w) };
        int col = (j < 32) ? j * 4 : 192 + (j - 32) * 4;
        *(us4*)(Ag + (size_t)b * 448 + col) = o;
    }

    // ---- scores: wave w -> rows [w*32, +32); coalesced Wr row loads + wave reduce ----
    {
        int w = t >> 6, l = t & 63;
        float4 hv = ((const float4*)(h + (size_t)b * 256))[l];
#pragma unroll 4
        for (int i = 0; i < 32; ++i) {
            int n = w * 32 + i;
            float4 wv = ((const float4*)(Wr + (size_t)n * 256))[l];
            float s = wv.x * hv.x + wv.y * hv.y + wv.z * hv.z + wv.w * hv.w;
#pragma unroll
            for (int mk = 32; mk >= 1; mk >>= 1) s += __shfl_xor(s, mk);
            if (l == 0) scr[n] = s + br[n];
        }
    }
    __syncthreads();
    // ---- softmax over 128 cols, one wave ----
    if (t < 64) {
        float v0 = scr[t], v1 = scr[t + 64];
        float m = fmaxf(v0, v1);
#pragma unroll
        for (int mk = 32; mk >= 1; mk >>= 1) m = fmaxf(m, __shfl_xor(m, mk));
        float e0 = __expf(v0 - m), e1 = __expf(v1 - m);
        float s = e0 + e1;
#pragma unroll
        for (int mk = 32; mk >= 1; mk >>= 1) s += __shfl_xor(s, mk);
        float inv = 1.f / s;
        wL[t] = e0 * inv;
        wL[t + 64] = e1 * inv;
    }
    __syncthreads();

    // ---- rv = wL . mem[b] stream ----
    int np = t >> 4, d4 = t & 15;
    const float4* m4 = (const float4*)(mem + (size_t)b * 8192);
    float4 acc = make_float4(0.f, 0.f, 0.f, 0.f);
#pragma unroll
    for (int j = 0; j < 8; ++j) {
        int n = np + 16 * j;
        float w = wL[n];
        float4 mv = m4[t + 256 * j];
        acc.x += w * mv.x; acc.y += w * mv.y; acc.z += w * mv.z; acc.w += w * mv.w;
    }
    part[np][d4 * 4 + 0] = acc.x; part[np][d4 * 4 + 1] = acc.y;
    part[np][d4 * 4 + 2] = acc.z; part[np][d4 * 4 + 3] = acc.w;
    __syncthreads();
    if (t < 64) {
        float s = 0.f;
#pragma unroll
        for (int q = 0; q < 16; ++q) s += part[q][t];
        unsigned short bv = f2bf(s);
        Ag[(size_t)b * 448 + 128 + t] = bv;
        Aout[(size_t)b * 320 + 256 + t] = bv;
    }
}

// =============== kB: gates GEMM [MFMA], BK=64 + LSTM (R11, proven) ===============
__global__ __launch_bounds__(256) void kB_gates(
    const unsigned short* __restrict__ Ag, const unsigned short* __restrict__ Wg,
    const float* __restrict__ bsum, const float* __restrict__ c,
    float* __restrict__ h_new, float* __restrict__ c_new,
    unsigned short* __restrict__ Aout)
{
    __shared__ unsigned short As[32 * 64];
    __shared__ unsigned short Bs[256 * 64];
    int t = threadIdx.x;
    int wid = t >> 6, lane = t & 63;
    int cl = lane & 15, ks = lane >> 4;
    int b0 = blockIdx.x * 32;
    int u0 = blockIdx.y * 64;

    int arow = t >> 3, aseg = t & 7;
    const unsigned short* aSrc = Ag + (size_t)(b0 + arow) * 448 + ((aseg ^ (arow & 7)) * 8);
    unsigned short* aDst = As + t * 8;
    const unsigned short* bSrc[8];
    unsigned short* bDst[8];
#pragma unroll
    for (int j = 0; j < 8; ++j) {
        int i = j * 256 + t;
        int rl = i >> 3, seg = i & 7;
        int g = rl >> 6, u = rl & 63;
        bSrc[j] = Wg + (size_t)(g * 256 + u0 + u) * 448 + ((seg ^ (rl & 7)) * 8);
        bDst[j] = Bs + i * 8;
    }

    int aOff[2][2];
#pragma unroll
    for (int rf = 0; rf < 2; ++rf)
#pragma unroll
        for (int kk = 0; kk < 2; ++kk) {
            int mr = rf * 16 + cl;
            aOff[rf][kk] = mr * 64 + (((kk * 4 + ks) ^ (cl & 7)) * 8);
        }
    int bOff[4][2];
#pragma unroll
    for (int g = 0; g < 4; ++g)
#pragma unroll
        for (int kk = 0; kk < 2; ++kk) {
            int br_ = g * 64 + wid * 16 + cl;
            bOff[g][kk] = br_ * 64 + (((kk * 4 + ks) ^ (cl & 7)) * 8);
        }

    f32x4 acc[2][4] = {};
    for (int kc = 0; kc < 7; ++kc) {
        __syncthreads();
        GLL16(aSrc, aDst);
#pragma unroll
        for (int j = 0; j < 8; ++j) GLL16(bSrc[j], bDst[j]);
        aSrc += 64;
#pragma unroll
        for (int j = 0; j < 8; ++j) bSrc[j] += 64;
        __syncthreads();
#pragma unroll
        for (int kk = 0; kk < 2; ++kk) {
            bf16x8 a[2], b[4];
#pragma unroll
            for (int rf = 0; rf < 2; ++rf) a[rf] = *(const bf16x8*)(As + aOff[rf][kk]);
#pragma unroll
            for (int g = 0; g < 4; ++g) b[g] = *(const bf16x8*)(Bs + bOff[g][kk]);
#pragma unroll
            for (int rf = 0; rf < 2; ++rf)
#pragma unroll
                for (int g = 0; g < 4; ++g)
                    acc[rf][g] = MFMA16(a[rf], b[g], acc[rf][g]);
        }
    }

    int unit = u0 + wid * 16 + cl;
    float bi = bsum[unit], bf_ = bsum[256 + unit];
    float bg = bsum[512 + unit], bo_ = bsum[768 + unit];
#pragma unroll
    for (int rf = 0; rf < 2; ++rf) {
#pragma unroll
        for (int r = 0; r < 4; ++r) {
            int row = b0 + rf * 16 + ks * 4 + r;
            float iv = sigf(acc[rf][0][r] + bi);
            float fv = sigf(acc[rf][1][r] + bf_);
            float gv = tanhf(acc[rf][2][r] + bg);
            float ov = sigf(acc[rf][3][r] + bo_);
            float cv = fv * c[(size_t)row * 256 + unit] + iv * gv;
            float hv = ov * tanhf(cv);
            c_new[(size_t)row * 256 + unit] = cv;
            h_new[(size_t)row * 256 + unit] = hv;
            Aout[(size_t)row * 320 + unit] = f2bf(hv);
        }
    }
}

// =============== kC: heads + out GEMM (512 blocks x 8 rows, R11 proven) ===============
__global__ __launch_bounds__(256) void kC_heads_out(
    const unsigned short* __restrict__ Aout, const unsigned short* __restrict__ Wh_b,
    const unsigned short* __restrict__ Wo_b, const float* __restrict__ bh_b,
    const float* __restrict__ bo, float* __restrict__ write_w,
    float* __restrict__ erase, float* __restrict__ addv, float* __restrict__ outp)
{
    __shared__ unsigned short As8[8 * 320];
    __shared__ unsigned short Bh[256 * 32];
    __shared__ unsigned short Bo[128 * 32];
    __shared__ float sc8[8][256];

    int t = threadIdx.x;
    int wid = t >> 6, lane = t & 63;
    int cl = lane & 15, ks = lane >> 4;
    int r0 = blockIdx.x * 8;

    for (int i = t; i < 640; i += 256) {
        int row = i / 80, c4 = (i - row * 80) * 4;
        us4 v = *(const us4*)(Aout + (size_t)(r0 + row) * 320 + c4);
        *(us4*)(As8 + swA8(row, c4)) = v;
    }

    const unsigned short* bhSrc[4];
    unsigned short* bhDst[4];
#pragma unroll
    for (int j = 0; j < 4; ++j) {
        int rl = (j * 256 + t) >> 2;
        bhSrc[j] = Wh_b + (size_t)rl * 256 + SW(rl, t & 3) * 8;
        bhDst[j] = Bh + (j * 256 + wid * 64) * 8;
    }
    const unsigned short* boSrc[2];
    unsigned short* boDst[2];
#pragma unroll
    for (int j = 0; j < 2; ++j) {
        int rj = j * 64 + (t >> 2);
        boSrc[j] = Wo_b + (size_t)rj * 320 + SW(rj, t & 3) * 8;
        boDst[j] = Bo + j * 2048 + wid * 512;
    }

    int bOffH[4], bOffO[2];
#pragma unroll
    for (int j = 0; j < 4; ++j) { int br_ = (wid + 4 * j) * 16 + cl; bOffH[j] = br_ * 32 + SW(br_, ks) * 8; }
#pragma unroll
    for (int j = 0; j < 2; ++j) { int br_ = (wid + 4 * j) * 16 + cl; bOffO[j] = br_ * 32 + SW(br_, ks) * 8; }

    f32x4 accH[4] = {};
    f32x4 accO[2] = {};
    for (int kc = 0; kc < 10; ++kc) {
        __syncthreads();
        if (kc < 8) {
            GLL16(bhSrc[0], bhDst[0]); GLL16(bhSrc[1], bhDst[1]);
            GLL16(bhSrc[2], bhDst[2]); GLL16(bhSrc[3], bhDst[3]);
#pragma unroll
            for (int j = 0; j < 4; ++j) bhSrc[j] += 32;
        }
        GLL16(boSrc[0], boDst[0]); GLL16(boSrc[1], boDst[1]);
#pragma unroll
        for (int j = 0; j < 2; ++j) boSrc[j] += 32;
        __syncthreads();
        bf16x8 a = *(const bf16x8*)(As8 + swA8(cl & 7, kc * 32 + ks * 8));
        if (kc < 8) {
#pragma unroll
            for (int j = 0; j < 4; ++j)
                accH[j] = MFMA16(a, *(const bf16x8*)(Bh + bOffH[j]), accH[j]);
        }
#pragma unroll
        for (int j = 0; j < 2; ++j)
            accO[j] = MFMA16(a, *(const bf16x8*)(Bo + bOffO[j]), accO[j]);
    }

    if (ks < 2) {
#pragma unroll
        for (int j = 0; j < 4; ++j) {
            int col = (wid + 4 * j) * 16 + cl;
            float bb = bh_b[col];
#pragma unroll
            for (int r = 0; r < 4; ++r) sc8[ks * 4 + r][col] = accH[j][r] + bb;
        }
#pragma unroll
        for (int j = 0; j < 2; ++j) {
            int ocol = (wid + 4 * j) * 16 + cl;
            float bb = bo[ocol];
#pragma unroll
            for (int r = 0; r < 4; ++r)
                outp[(size_t)(r0 + ks * 4 + r) * 128 + ocol] = accO[j][r] + bb;
        }
    }
    __syncthreads();

    if (t < 128) {
        int row = t >> 4, l = t & 15;
        float v[8];
#pragma unroll
        for (int j = 0; j < 8; ++j) v[j] = sc8[row][l + 16 * j];
        float m = v[0];
#pragma unroll
        for (int j = 1; j < 8; ++j) m = fmaxf(m, v[j]);
#pragma unroll
        for (int mk = 8; mk >= 1; mk >>= 1) m = fmaxf(m, __shfl_xor(m, mk));
        float s = 0.f;
#pragma unroll
        for (int j = 0; j < 8; ++j) { v[j] = __expf(v[j] - m); s += v[j]; }
#pragma unroll
        for (int mk = 8; mk >= 1; mk >>= 1) s += __shfl_xor(s, mk);
        float inv = 1.f / s;
        int row_g = r0 + row;
#pragma unroll
        for (int j = 0; j < 8; ++j)
            write_w[(size_t)row_g * 128 + l + 16 * j] = v[j] * inv;
#pragma unroll
        for (int j = 0; j < 4; ++j)
            erase[(size_t)row_g * 64 + l + 16 * j] = sigf(sc8[row][128 + l + 16 * j]);
#pragma unroll
        for (int j = 0; j < 4; ++j)
            addv[(size_t)row_g * 64 + l + 16 * j] = tanhf(sc8[row][192 + l + 16 * j]);
    }
}

// =============== k5: pure mem RMW stream (grid 4096, NT stores, proven) ===============
__global__ __launch_bounds__(256) void k5_mem_update(
    const float* __restrict__ mem, const float* __restrict__ write_w,
    const float* __restrict__ erase, const float* __restrict__ addv,
    float* __restrict__ mem_new)
{
    int t = threadIdx.x; int b = blockIdx.x;
    int np = t >> 4, d0 = (t & 15) * 4;
    const f32x4* m4 = (const f32x4*)(mem + (size_t)b * 8192);
    f32x4* o4 = (f32x4*)(mem_new + (size_t)b * 8192);
    f32x4 e4 = *(const f32x4*)(erase + (size_t)b * 64 + d0);
    f32x4 a4 = *(const f32x4*)(addv + (size_t)b * 64 + d0);
#pragma unroll
    for (int j = 0; j < 8; ++j) {
        int n = np + 16 * j;
        float w = write_w[(size_t)b * 128 + n];
        f32x4 m = m4[t + 256 * j];
        f32x4 r;
        r[0] = m[0] * (1.f - w * e4[0]) + w * a4[0];
        r[1] = m[1] * (1.f - w * e4[1]) + w * a4[1];
        r[2] = m[2] * (1.f - w * e4[2]) + w * a4[2];
        r[3] = m[3] * (1.f - w * e4[3]) + w * a4[3];
        __builtin_nontemporal_store(r, &o4[t + 256 * j]);
    }
}

extern "C" void kernel_launch(void* const* d_in, const int* in_sizes, int n_in,
                              void* d_out, int out_size, void* d_ws, size_t ws_size,
                              hipStream_t stream)
{
    const float* x    = (const float*)d_in[0];
    const float* mem  = (const float*)d_in[1];
    const float* h    = (const float*)d_in[2];
    const float* c    = (const float*)d_in[3];
    const float* Wih  = (const float*)d_in[4];
    const float* Whh  = (const float*)d_in[5];
    const float* bih  = (const float*)d_in[6];
    const float* bhh  = (const float*)d_in[7];
    const float* Wr   = (const float*)d_in[8];
    const float* br   = (const float*)d_in[9];
    const float* Ww   = (const float*)d_in[10];
    const float* bw   = (const float*)d_in[11];
    const float* We   = (const float*)d_in[12];
    const float* be   = (const float*)d_in[13];
    const float* Wa   = (const float*)d_in[14];
    const float* ba   = (const float*)d_in[15];
    const float* Wo   = (const float*)d_in[16];
    const float* bo   = (const float*)d_in[17];

    float* out     = (float*)d_out;
    float* mem_new = out + 524288;
    float* h_new   = out + 34078720;
    float* c_new   = out + 35127296;

    float* ws      = (float*)d_ws;
    float* write_w = ws + 524288;              // 524288
    float* erase   = ws + 1048576;             // 262144
    float* addv    = ws + 1310720;             // 262144
    float* bsum    = ws + 1572864;             // 1024
    float* bh_b    = ws + 1573888;             // 256
    unsigned short* ub   = (unsigned short*)(ws + 1574144);
    unsigned short* Ag   = ub;                 // 1835008
    unsigned short* Aout = ub + 1835008;       // 1310720
    unsigned short* Wg   = ub + 3145728;       // 458752
    unsigned short* Wh_b = ub + 3604480;       // 65536
    unsigned short* Wo_b = ub + 3670016;       // 40960

    k2_stream_pack<<<4096, 256, 0, stream>>>(mem, x, h, Wih, Whh, bih, bhh, Wr, br,
                                             Ww, We, Wa, bw, be, ba, Wo,
                                             Wg, Wh_b, Wo_b, bsum, bh_b, Ag, Aout);
    kB_gates<<<dim3(128, 4), 256, 0, stream>>>(Ag, Wg, bsum, c, h_new, c_new, Aout);
    kC_heads_out<<<512, 256, 0, stream>>>(Aout, Wh_b, Wo_b, bh_b, bo,
                                          write_w, erase, addv, out);
    k5_mem_update<<<4096, 256, 0, stream>>>(mem, write_w, erase, addv, mem_new);
}

// Round 13
// 103.254 us; speedup vs baseline: 1.2453x; 1.2453x over previous
//
#include <hip/hip_runtime.h>
#include <math.h>

// Shapes: B=4096, N=128, D=64, H=256, O=128
// d_out (floats): out[B*128] | mem_new[B*128*64] | h_new[B*256] | c_new[B*256]
// ws: read_w f32 | write_w f32 | erase f32 | addv f32 | bsum f32 | bh_b f32 |
//     bf16: Ag[4096][448]=[x|rv|h] | Aout[4096][320]=[h_new|rv] | Wg[1024][448] |
//           Wh_b[256][256] | Wo_b[128][320]

typedef __attribute__((ext_vector_type(8))) short bf16x8;
typedef __attribute__((ext_vector_type(4))) float f32x4;
typedef __attribute__((ext_vector_type(4))) unsigned short us4;

#define MFMA16(a, b, c) __builtin_amdgcn_mfma_f32_16x16x32_bf16(a, b, c, 0, 0, 0)
#define GLL16(gp, lp) __builtin_amdgcn_global_load_lds( \
    (const __attribute__((address_space(1))) void*)(gp), \
    (__attribute__((address_space(3))) void*)(lp), 16, 0, 0)
#define SW(row, s) ((s) ^ ((row) & 3))

__device__ __forceinline__ float sigf(float v) { return 1.f / (1.f + __expf(-v)); }

__device__ __forceinline__ unsigned short f2bf(float f) {
    unsigned u = __builtin_bit_cast(unsigned, f);
    u = (u + 0x7FFFu + ((u >> 16) & 1u)) >> 16;
    return (unsigned short)u;
}

// swizzled addr in an [8][320] bf16 LDS tile (4-group XOR within 32-col chunks)
__device__ __forceinline__ int swA8(int r, int c) {
    return r * 320 + (c & ~31) + ((((c >> 3) & 3) ^ (r & 3)) << 3) + (c & 7);
}

// =============== kA: read-attn scores + softmax -> read_w (R7/R9, proven) ===============
__global__ __launch_bounds__(256) void kA_scores(
    const float* __restrict__ h, const float* __restrict__ Wr,
    const float* __restrict__ br, float* __restrict__ read_w)
{
    __shared__ unsigned short As[16 * 32];
    __shared__ unsigned short Bs[128 * 32];
    __shared__ float sc[16][128];

    int t = threadIdx.x;
    int wid = t >> 6, lane = t & 63;
    int cl = lane & 15, ks = lane >> 4;
    int b0 = blockIdx.x * 16;

    int aOff = cl * 32 + SW(cl, ks) * 8;
    int bOff[4];
#pragma unroll
    for (int f = 0; f < 4; ++f) {
        int br_ = (wid * 4 + f) * 16 + cl;
        bOff[f] = br_ * 32 + SW(br_, ks) * 8;
    }
    f32x4 acc[4] = {};
    for (int kc = 0; kc < 8; ++kc) {
        __syncthreads();
        {
            int row = t >> 4, k0 = (t & 15) * 2;
            float2 hv = *(const float2*)(h + (size_t)(b0 + row) * 256 + kc * 32 + k0);
            unsigned pk = (unsigned)f2bf(hv.x) | ((unsigned)f2bf(hv.y) << 16);
            *(unsigned*)(As + row * 32 + SW(row, k0 >> 3) * 8 + (k0 & 7)) = pk;
        }
        {
            int row = t >> 1, k0 = (t & 1) * 16;
            const float4* wp = (const float4*)(Wr + (size_t)row * 256 + kc * 32 + k0);
            float4 w0 = wp[0], w1 = wp[1], w2 = wp[2], w3 = wp[3];
            us4 p0 = { f2bf(w0.x), f2bf(w0.y), f2bf(w0.z), f2bf(w0.w) };
            us4 p1 = { f2bf(w1.x), f2bf(w1.y), f2bf(w1.z), f2bf(w1.w) };
            us4 p2 = { f2bf(w2.x), f2bf(w2.y), f2bf(w2.z), f2bf(w2.w) };
            us4 p3 = { f2bf(w3.x), f2bf(w3.y), f2bf(w3.z), f2bf(w3.w) };
            int g0 = k0 >> 3;
            unsigned short* basep = Bs + row * 32;
            *(us4*)(basep + SW(row, g0) * 8)         = p0;
            *(us4*)(basep + SW(row, g0) * 8 + 4)     = p1;
            *(us4*)(basep + SW(row, g0 + 1) * 8)     = p2;
            *(us4*)(basep + SW(row, g0 + 1) * 8 + 4) = p3;
        }
        __syncthreads();
        if (wid < 2) {
            bf16x8 a = *(const bf16x8*)(As + aOff);
#pragma unroll
            for (int f = 0; f < 4; ++f)
                acc[f] = MFMA16(a, *(const bf16x8*)(Bs + bOff[f]), acc[f]);
        }
    }
    if (wid < 2) {
#pragma unroll
        for (int f = 0; f < 4; ++f)
#pragma unroll
            for (int r = 0; r < 4; ++r)
                sc[ks * 4 + r][(wid * 4 + f) * 16 + cl] = acc[f][r];
    }
    __syncthreads();
    {
        int row = t >> 4, l = t & 15;
        float v[8];
#pragma unroll
        for (int j = 0; j < 8; ++j) v[j] = sc[row][l + 16 * j] + br[l + 16 * j];
        float m = v[0];
#pragma unroll
        for (int j = 1; j < 8; ++j) m = fmaxf(m, v[j]);
#pragma unroll
        for (int mk = 8; mk >= 1; mk >>= 1) m = fmaxf(m, __shfl_xor(m, mk));
        float s = 0.f;
#pragma unroll
        for (int j = 0; j < 8; ++j) { v[j] = __expf(v[j] - m); s += v[j]; }
#pragma unroll
        for (int mk = 8; mk >= 1; mk >>= 1) s += __shfl_xor(s, mk);
        float inv = 1.f / s;
#pragma unroll
        for (int j = 0; j < 8; ++j)
            read_w[(size_t)(b0 + row) * 128 + l + 16 * j] = v[j] * inv;
    }
}

// =============== k2: pack (striped) + rv stream (R9, proven) ===============
__global__ __launch_bounds__(256) void k2_stream_pack(
    const float* __restrict__ mem, const float* __restrict__ read_w,
    const float* __restrict__ x, const float* __restrict__ h,
    const float* __restrict__ Wih, const float* __restrict__ Whh,
    const float* __restrict__ bih, const float* __restrict__ bhh,
    const float* __restrict__ Ww, const float* __restrict__ We,
    const float* __restrict__ Wa, const float* __restrict__ bw,
    const float* __restrict__ be, const float* __restrict__ ba,
    const float* __restrict__ Wo,
    unsigned short* __restrict__ Wg, unsigned short* __restrict__ Wh_b,
    unsigned short* __restrict__ Wo_b, float* __restrict__ bsum,
    float* __restrict__ bh_b, unsigned short* __restrict__ Ag,
    unsigned short* __restrict__ Aout)
{
    __shared__ float part[16][68];
    int t = threadIdx.x;
    int b = blockIdx.x;
    unsigned idx = b * 256 + t;

    if (idx < 458752) {
        int r = idx / 448, cc = idx - r * 448;
        float v = (cc < 192) ? Wih[(size_t)r * 192 + cc] : Whh[(size_t)r * 256 + (cc - 192)];
        Wg[idx] = f2bf(v);
    }
    if (idx < 65536) {
        int r = idx >> 8, cc = idx & 255;
        float v = (r < 128) ? Ww[(size_t)r * 256 + cc]
                : (r < 192) ? We[(size_t)(r - 128) * 256 + cc]
                            : Wa[(size_t)(r - 192) * 256 + cc];
        Wh_b[idx] = f2bf(v);
    }
    if (idx < 40960) Wo_b[idx] = f2bf(Wo[idx]);
    if (idx < 1024)  bsum[idx] = bih[idx] + bhh[idx];
    if (idx < 256)
        bh_b[idx] = (idx < 128) ? bw[idx] : (idx < 192 ? be[idx - 128] : ba[idx - 192]);

    if (t < 96) {
        int j = t;
        float4 v = (j < 32) ? ((const float4*)(x + (size_t)b * 128))[j]
                            : ((const float4*)(h + (size_t)b * 256))[j - 32];
        us4 o = { f2bf(v.x), f2bf(v.y), f2bf(v.z), f2bf(v.w) };
        int col = (j < 32) ? j * 4 : 192 + (j - 32) * 4;
        *(us4*)(Ag + (size_t)b * 448 + col) = o;
    }

    int np = t >> 4, d4 = t & 15;
    const float4* m4 = (const float4*)(mem + (size_t)b * 8192);
    float4 acc = make_float4(0.f, 0.f, 0.f, 0.f);
#pragma unroll
    for (int j = 0; j < 8; ++j) {
        int n = np + 16 * j;
        float w = read_w[(size_t)b * 128 + n];
        float4 mv = m4[t + 256 * j];
        acc.x += w * mv.x; acc.y += w * mv.y; acc.z += w * mv.z; acc.w += w * mv.w;
    }
    part[np][d4 * 4 + 0] = acc.x; part[np][d4 * 4 + 1] = acc.y;
    part[np][d4 * 4 + 2] = acc.z; part[np][d4 * 4 + 3] = acc.w;
    __syncthreads();
    if (t < 64) {
        float s = 0.f;
#pragma unroll
        for (int q = 0; q < 16; ++q) s += part[q][t];
        unsigned short bv = f2bf(s);
        Ag[(size_t)b * 448 + 128 + t] = bv;
        Aout[(size_t)b * 320 + 256 + t] = bv;
    }
}

// =============== kB: gates GEMM [MFMA], BK=64 (7 K-iters) + LSTM (R11, proven) ===============
__global__ __launch_bounds__(256) void kB_gates(
    const unsigned short* __restrict__ Ag, const unsigned short* __restrict__ Wg,
    const float* __restrict__ bsum, const float* __restrict__ c,
    float* __restrict__ h_new, float* __restrict__ c_new,
    unsigned short* __restrict__ Aout)
{
    __shared__ unsigned short As[32 * 64];
    __shared__ unsigned short Bs[256 * 64];
    int t = threadIdx.x;
    int wid = t >> 6, lane = t & 63;
    int cl = lane & 15, ks = lane >> 4;
    int b0 = blockIdx.x * 32;
    int u0 = blockIdx.y * 64;

    int arow = t >> 3, aseg = t & 7;
    const unsigned short* aSrc = Ag + (size_t)(b0 + arow) * 448 + ((aseg ^ (arow & 7)) * 8);
    unsigned short* aDst = As + t * 8;
    const unsigned short* bSrc[8];
    unsigned short* bDst[8];
#pragma unroll
    for (int j = 0; j < 8; ++j) {
        int i = j * 256 + t;
        int rl = i >> 3, seg = i & 7;
        int g = rl >> 6, u = rl & 63;
        bSrc[j] = Wg + (size_t)(g * 256 + u0 + u) * 448 + ((seg ^ (rl & 7)) * 8);
        bDst[j] = Bs + i * 8;
    }

    int aOff[2][2];
#pragma unroll
    for (int rf = 0; rf < 2; ++rf)
#pragma unroll
        for (int kk = 0; kk < 2; ++kk) {
            int mr = rf * 16 + cl;
            aOff[rf][kk] = mr * 64 + (((kk * 4 + ks) ^ (cl & 7)) * 8);
        }
    int bOff[4][2];
#pragma unroll
    for (int g = 0; g < 4; ++g)
#pragma unroll
        for (int kk = 0; kk < 2; ++kk) {
            int br_ = g * 64 + wid * 16 + cl;
            bOff[g][kk] = br_ * 64 + (((kk * 4 + ks) ^ (cl & 7)) * 8);
        }

    f32x4 acc[2][4] = {};
    for (int kc = 0; kc < 7; ++kc) {
        __syncthreads();
        GLL16(aSrc, aDst);
#pragma unroll
        for (int j = 0; j < 8; ++j) GLL16(bSrc[j], bDst[j]);
        aSrc += 64;
#pragma unroll
        for (int j = 0; j < 8; ++j) bSrc[j] += 64;
        __syncthreads();
#pragma unroll
        for (int kk = 0; kk < 2; ++kk) {
            bf16x8 a[2], b[4];
#pragma unroll
            for (int rf = 0; rf < 2; ++rf) a[rf] = *(const bf16x8*)(As + aOff[rf][kk]);
#pragma unroll
            for (int g = 0; g < 4; ++g) b[g] = *(const bf16x8*)(Bs + bOff[g][kk]);
#pragma unroll
            for (int rf = 0; rf < 2; ++rf)
#pragma unroll
                for (int g = 0; g < 4; ++g)
                    acc[rf][g] = MFMA16(a[rf], b[g], acc[rf][g]);
        }
    }

    int unit = u0 + wid * 16 + cl;
    float bi = bsum[unit], bf_ = bsum[256 + unit];
    float bg = bsum[512 + unit], bo_ = bsum[768 + unit];
#pragma unroll
    for (int rf = 0; rf < 2; ++rf) {
#pragma unroll
        for (int r = 0; r < 4; ++r) {
            int row = b0 + rf * 16 + ks * 4 + r;
            float iv = sigf(acc[rf][0][r] + bi);
            float fv = sigf(acc[rf][1][r] + bf_);
            float gv = tanhf(acc[rf][2][r] + bg);
            float ov = sigf(acc[rf][3][r] + bo_);
            float cv = fv * c[(size_t)row * 256 + unit] + iv * gv;
            float hv = ov * tanhf(cv);
            c_new[(size_t)row * 256 + unit] = cv;
            h_new[(size_t)row * 256 + unit] = hv;
            Aout[(size_t)row * 320 + unit] = f2bf(hv);
        }
    }
}

// =============== kC: heads + out GEMM (512 blocks x 8 rows, R11 proven) ===============
__global__ __launch_bounds__(256) void kC_heads_out(
    const unsigned short* __restrict__ Aout, const unsigned short* __restrict__ Wh_b,
    const unsigned short* __restrict__ Wo_b, const float* __restrict__ bh_b,
    const float* __restrict__ bo, float* __restrict__ write_w,
    float* __restrict__ erase, float* __restrict__ addv, float* __restrict__ outp)
{
    __shared__ unsigned short As8[8 * 320];
    __shared__ unsigned short Bh[256 * 32];
    __shared__ unsigned short Bo[128 * 32];
    __shared__ float sc8[8][256];

    int t = threadIdx.x;
    int wid = t >> 6, lane = t & 63;
    int cl = lane & 15, ks = lane >> 4;
    int r0 = blockIdx.x * 8;

    for (int i = t; i < 640; i += 256) {
        int row = i / 80, c4 = (i - row * 80) * 4;
        us4 v = *(const us4*)(Aout + (size_t)(r0 + row) * 320 + c4);
        *(us4*)(As8 + swA8(row, c4)) = v;
    }

    const unsigned short* bhSrc[4];
    unsigned short* bhDst[4];
#pragma unroll
    for (int j = 0; j < 4; ++j) {
        int rl = (j * 256 + t) >> 2;
        bhSrc[j] = Wh_b + (size_t)rl * 256 + SW(rl, t & 3) * 8;
        bhDst[j] = Bh + (j * 256 + wid * 64) * 8;
    }
    const unsigned short* boSrc[2];
    unsigned short* boDst[2];
#pragma unroll
    for (int j = 0; j < 2; ++j) {
        int rj = j * 64 + (t >> 2);
        boSrc[j] = Wo_b + (size_t)rj * 320 + SW(rj, t & 3) * 8;
        boDst[j] = Bo + j * 2048 + wid * 512;
    }

    int bOffH[4], bOffO[2];
#pragma unroll
    for (int j = 0; j < 4; ++j) { int br_ = (wid + 4 * j) * 16 + cl; bOffH[j] = br_ * 32 + SW(br_, ks) * 8; }
#pragma unroll
    for (int j = 0; j < 2; ++j) { int br_ = (wid + 4 * j) * 16 + cl; bOffO[j] = br_ * 32 + SW(br_, ks) * 8; }

    f32x4 accH[4] = {};
    f32x4 accO[2] = {};
    for (int kc = 0; kc < 10; ++kc) {
        __syncthreads();
        if (kc < 8) {
            GLL16(bhSrc[0], bhDst[0]); GLL16(bhSrc[1], bhDst[1]);
            GLL16(bhSrc[2], bhDst[2]); GLL16(bhSrc[3], bhDst[3]);
#pragma unroll
            for (int j = 0; j < 4; ++j) bhSrc[j] += 32;
        }
        GLL16(boSrc[0], boDst[0]); GLL16(boSrc[1], boDst[1]);
#pragma unroll
        for (int j = 0; j < 2; ++j) boSrc[j] += 32;
        __syncthreads();
        bf16x8 a = *(const bf16x8*)(As8 + swA8(cl & 7, kc * 32 + ks * 8));
        if (kc < 8) {
#pragma unroll
            for (int j = 0; j < 4; ++j)
                accH[j] = MFMA16(a, *(const bf16x8*)(Bh + bOffH[j]), accH[j]);
        }
#pragma unroll
        for (int j = 0; j < 2; ++j)
            accO[j] = MFMA16(a, *(const bf16x8*)(Bo + bOffO[j]), accO[j]);
    }

    if (ks < 2) {
#pragma unroll
        for (int j = 0; j < 4; ++j) {
            int col = (wid + 4 * j) * 16 + cl;
            float bb = bh_b[col];
#pragma unroll
            for (int r = 0; r < 4; ++r) sc8[ks * 4 + r][col] = accH[j][r] + bb;
        }
#pragma unroll
        for (int j = 0; j < 2; ++j) {
            int ocol = (wid + 4 * j) * 16 + cl;
            float bb = bo[ocol];
#pragma unroll
            for (int r = 0; r < 4; ++r)
                outp[(size_t)(r0 + ks * 4 + r) * 128 + ocol] = accO[j][r] + bb;
        }
    }
    __syncthreads();

    if (t < 128) {
        int row = t >> 4, l = t & 15;
        float v[8];
#pragma unroll
        for (int j = 0; j < 8; ++j) v[j] = sc8[row][l + 16 * j];
        float m = v[0];
#pragma unroll
        for (int j = 1; j < 8; ++j) m = fmaxf(m, v[j]);
#pragma unroll
        for (int mk = 8; mk >= 1; mk >>= 1) m = fmaxf(m, __shfl_xor(m, mk));
        float s = 0.f;
#pragma unroll
        for (int j = 0; j < 8; ++j) { v[j] = __expf(v[j] - m); s += v[j]; }
#pragma unroll
        for (int mk = 8; mk >= 1; mk >>= 1) s += __shfl_xor(s, mk);
        float inv = 1.f / s;
        int row_g = r0 + row;
#pragma unroll
        for (int j = 0; j < 8; ++j)
            write_w[(size_t)row_g * 128 + l + 16 * j] = v[j] * inv;
#pragma unroll
        for (int j = 0; j < 4; ++j)
            erase[(size_t)row_g * 64 + l + 16 * j] = sigf(sc8[row][128 + l + 16 * j]);
#pragma unroll
        for (int j = 0; j < 4; ++j)
            addv[(size_t)row_g * 64 + l + 16 * j] = tanhf(sc8[row][192 + l + 16 * j]);
    }
}

// =============== k5: pure mem RMW stream (grid 4096, NT stores, proven) ===============
__global__ __launch_bounds__(256) void k5_mem_update(
    const float* __restrict__ mem, const float* __restrict__ write_w,
    const float* __restrict__ erase, const float* __restrict__ addv,
    float* __restrict__ mem_new)
{
    int t = threadIdx.x; int b = blockIdx.x;
    int np = t >> 4, d0 = (t & 15) * 4;
    const f32x4* m4 = (const f32x4*)(mem + (size_t)b * 8192);
    f32x4* o4 = (f32x4*)(mem_new + (size_t)b * 8192);
    f32x4 e4 = *(const f32x4*)(erase + (size_t)b * 64 + d0);
    f32x4 a4 = *(const f32x4*)(addv + (size_t)b * 64 + d0);
#pragma unroll
    for (int j = 0; j < 8; ++j) {
        int n = np + 16 * j;
        float w = write_w[(size_t)b * 128 + n];
        f32x4 m = m4[t + 256 * j];
        f32x4 r;
        r[0] = m[0] * (1.f - w * e4[0]) + w * a4[0];
        r[1] = m[1] * (1.f - w * e4[1]) + w * a4[1];
        r[2] = m[2] * (1.f - w * e4[2]) + w * a4[2];
        r[3] = m[3] * (1.f - w * e4[3]) + w * a4[3];
        __builtin_nontemporal_store(r, &o4[t + 256 * j]);
    }
}

extern "C" void kernel_launch(void* const* d_in, const int* in_sizes, int n_in,
                              void* d_out, int out_size, void* d_ws, size_t ws_size,
                              hipStream_t stream)
{
    const float* x    = (const float*)d_in[0];
    const float* mem  = (const float*)d_in[1];
    const float* h    = (const float*)d_in[2];
    const float* c    = (const float*)d_in[3];
    const float* Wih  = (const float*)d_in[4];
    const float* Whh  = (const float*)d_in[5];
    const float* bih  = (const float*)d_in[6];
    const float* bhh  = (const float*)d_in[7];
    const float* Wr   = (const float*)d_in[8];
    const float* br   = (const float*)d_in[9];
    const float* Ww   = (const float*)d_in[10];
    const float* bw   = (const float*)d_in[11];
    const float* We   = (const float*)d_in[12];
    const float* be   = (const float*)d_in[13];
    const float* Wa   = (const float*)d_in[14];
    const float* ba   = (const float*)d_in[15];
    const float* Wo   = (const float*)d_in[16];
    const float* bo   = (const float*)d_in[17];

    float* out     = (float*)d_out;
    float* mem_new = out + 524288;
    float* h_new   = out + 34078720;
    float* c_new   = out + 35127296;

    float* ws      = (float*)d_ws;
    float* read_w  = ws;                       // 524288
    float* write_w = ws + 524288;              // 524288
    float* erase   = ws + 1048576;             // 262144
    float* addv    = ws + 1310720;             // 262144
    float* bsum    = ws + 1572864;             // 1024
    float* bh_b    = ws + 1573888;             // 256
    unsigned short* ub   = (unsigned short*)(ws + 1574144);
    unsigned short* Ag   = ub;                 // 1835008
    unsigned short* Aout = ub + 1835008;       // 1310720
    unsigned short* Wg   = ub + 3145728;       // 458752
    unsigned short* Wh_b = ub + 3604480;       // 65536
    unsigned short* Wo_b = ub + 3670016;       // 40960

    kA_scores<<<256, 256, 0, stream>>>(h, Wr, br, read_w);
    k2_stream_pack<<<4096, 256, 0, stream>>>(mem, read_w, x, h, Wih, Whh, bih, bhh,
                                             Ww, We, Wa, bw, be, ba, Wo,
                                             Wg, Wh_b, Wo_b, bsum, bh_b, Ag, Aout);
    kB_gates<<<dim3(128, 4), 256, 0, stream>>>(Ag, Wg, bsum, c, h_new, c_new, Aout);
    kC_heads_out<<<512, 256, 0, stream>>>(Aout, Wh_b, Wo_b, bh_b, bo,
                                          write_w, erase, addv, out);
    k5_mem_update<<<4096, 256, 0, stream>>>(mem, write_w, erase, addv, mem_new);
}